// Round 21
// baseline (110.618 us; speedup 1.0000x reference)
//
#include <hip/hip_runtime.h>
#include <math.h>

#define DIM 256

// ---------------------------------------------------------------------------
// K0 setup (4 blocks, one per output qubit q): builds M[q] = T[q] reshaped as
// 16x16 over (j=p0*4+p1, k=p2*4+p3) in d_ws. Validated math (rounds 2-20).
// z_q(row) = sum_{j,k} u_j M[q][j][k] v_k,  u = a0(x)a1, v = a2(x)a3,
// a_i = (1, Ax_i, Ay_i, Az_i) Bloch components; depolarize folded as
// s^(1+nnz), s = 1-4*0.05/3.  Qubit q <-> index bit (3-q).
// ---------------------------------------------------------------------------
__global__ void qc_setup_kernel(const float* __restrict__ qw, float* __restrict__ T)
{
  __shared__ float Vr[16][16], Vi[16][16];
  __shared__ float Or[16][16], Oi[16][16];
  const int tid = threadIdx.x;
  const int r = tid >> 4, c = tid & 15;

  Vr[r][c] = (r == c) ? 1.0f : 0.0f;
  Vi[r][c] = 0.0f;
  __syncthreads();

  #pragma unroll 1
  for (int i = 0; i < 4; ++i) {
    const int cm = 8 >> i;             // control mask (qubit i)
    const int tm = 8 >> ((i + 1) & 3); // target mask (qubit (i+1)%4)
    // CNOT(control=i, target=(i+1)%4): row permutation
    {
      const int k = (r & cm) ? (r ^ tm) : r;
      const float nr = Vr[k][c], ni = Vi[k][c];
      __syncthreads();
      Vr[r][c] = nr; Vi[r][c] = ni;
      __syncthreads();
    }
    const float w  = qw[4 + i];        // qweights[1][i]
    const float ch = cosf(0.5f * w), sh = sinf(0.5f * w);
    // RY(w) on qubit i
    {
      const int m = 8 >> i;
      const int r0 = r & ~m, r1 = r | m;
      float u0, u1;
      if (r & m) { u0 = sh; u1 = ch; } else { u0 = ch; u1 = -sh; }
      const float nr = u0 * Vr[r0][c] + u1 * Vr[r1][c];
      const float ni = u0 * Vi[r0][c] + u1 * Vi[r1][c];
      __syncthreads();
      Vr[r][c] = nr; Vi[r][c] = ni;
      __syncthreads();
    }
    // RZ(w) on qubit i (diagonal)
    {
      const int m = 8 >> i;
      const float pr = ch;
      const float pi = (r & m) ? sh : -sh;
      const float vr = Vr[r][c], vi = Vi[r][c];
      Vr[r][c] = pr * vr - pi * vi;
      Vi[r][c] = pr * vi + pi * vr;
      __syncthreads();
    }
  }

  const int q  = blockIdx.x;           // one q per block
  const int zm = 8 >> q;
  // O[r][c] = sum_k conj(V[k][r]) * sign_q(k) * V[k][c]
  float orr = 0.0f, oii = 0.0f;
  for (int k = 0; k < 16; ++k) {
    const float sgn = (k & zm) ? -1.0f : 1.0f;
    const float ar = Vr[k][r], ai = -Vi[k][r];
    const float br = Vr[k][c], bi = Vi[k][c];
    orr += sgn * (ar * br - ai * bi);
    oii += sgn * (ar * bi + ai * br);
  }
  __syncthreads();
  Or[r][c] = orr; Oi[r][c] = oii;
  __syncthreads();

  // thread tid <-> Pauli string p; Tr(P O) = sum_n P[n][m(n)] * O[m(n)][n]
  const float sdep = 1.0f - 4.0f * 0.05f / 3.0f;
  const int p0 = tid >> 6, p1 = (tid >> 4) & 3, p2 = (tid >> 2) & 3, p3 = tid & 3;
  float tr = 0.0f;
  for (int n = 0; n < 16; ++n) {
    int m = n;
    float fr = 1.0f, fi = 0.0f;
    #pragma unroll
    for (int i2 = 0; i2 < 4; ++i2) {
      const int a   = (n >> (3 - i2)) & 1;
      const int pi_ = (i2 == 0) ? p0 : (i2 == 1) ? p1 : (i2 == 2) ? p2 : p3;
      if (pi_ == 1) {                    // X
        m ^= (8 >> i2);
      } else if (pi_ == 2) {             // Y
        m ^= (8 >> i2);
        const float s2  = a ? 1.0f : -1.0f;
        const float nfr = -fi * s2, nfi = fr * s2;
        fr = nfr; fi = nfi;
      } else if (pi_ == 3) {             // Z
        if (a) { fr = -fr; fi = -fi; }
      }
    }
    tr += fr * Or[m][n] - fi * Oi[m][n];
  }
  const int nnz = (p0 != 0) + (p1 != 0) + (p2 != 0) + (p3 != 0);
  float scale = 1.0f / 16.0f;
  for (int e = 0; e <= nnz; ++e) scale *= sdep;
  T[q * 256 + tid] = tr * scale;
}

// ---------------------------------------------------------------------------
// Main kernel (round-21): TRANSPOSED-GEMV layout — reduction axis inside the
// thread, lanes span rows. thread = (row rl=lane&15, quarter kq=lane>>4).
// No LDS, no barriers, 2 shuffle steps total, z fully lane-local.
//   GEMV : 16 private float4 x-loads (64 distinct 64B lines per wave-instr,
//          consecutive j consume each line -> traffic at floor) + Win from L1.
//   combine: shfl_xor(16)+shfl_xor(32) -> every lane has its row's acc[4].
//   middle: per-lane (4x redundant), validated math; z in-register.
//   epilogue: re-read own x-quarter (L2/L3-hot) + store own out-quarter.
// In-flight bytes/CU ~ 16 indep loads x 16B x 256 thr ~ 65KB >> 9KB needed
// (Little's law fix without LDS/DMA). Live set ~56 VGPR -> fits the proven
// 64-reg spill-free allocation.
// ---------------------------------------------------------------------------
__global__ __launch_bounds__(256) void qlayer_main_kernel(
    const float* __restrict__ x,
    const float* __restrict__ Win,
    const float* __restrict__ b_in,
    const float* __restrict__ gamma,
    const float* __restrict__ beta,
    const float* __restrict__ qw,
    const float* __restrict__ Wout,
    const float* __restrict__ b_out,
    const float* __restrict__ M,
    float* __restrict__ out,
    int B)
{
  const int tid  = threadIdx.x;
  const int lane = tid & 63;
  const int wid  = blockIdx.x * (blockDim.x >> 6) + (tid >> 6);
  const int rl   = lane & 15;          // row within wave's 16
  const int kq   = lane >> 4;          // k-quarter 0..3
  const int row  = wid * 16 + rl;
  if (row >= B) return;

  const size_t xbase = (size_t)row * DIM + kq * 64;

  // ================= GEMV over my quarter: 16 private float4 loads =========
  float a0 = 0.0f, a1 = 0.0f, a2 = 0.0f, a3 = 0.0f;
  #pragma unroll
  for (int j = 0; j < 16; ++j) {
    const float4 xv = *reinterpret_cast<const float4*>(&x[xbase + j * 4]);
    const float4 w0 = *reinterpret_cast<const float4*>(&Win[0 * 256 + kq * 64 + j * 4]);
    const float4 w1 = *reinterpret_cast<const float4*>(&Win[1 * 256 + kq * 64 + j * 4]);
    const float4 w2 = *reinterpret_cast<const float4*>(&Win[2 * 256 + kq * 64 + j * 4]);
    const float4 w3 = *reinterpret_cast<const float4*>(&Win[3 * 256 + kq * 64 + j * 4]);
    a0 += xv.x * w0.x + xv.y * w0.y + xv.z * w0.z + xv.w * w0.w;
    a1 += xv.x * w1.x + xv.y * w1.y + xv.z * w1.z + xv.w * w1.w;
    a2 += xv.x * w2.x + xv.y * w2.y + xv.z * w2.z + xv.w * w2.w;
    a3 += xv.x * w3.x + xv.y * w3.y + xv.z * w3.z + xv.w * w3.w;
  }
  // combine quarters across lanes differing in bits 4,5 (same rl)
  a0 += __shfl_xor(a0, 16, 64); a1 += __shfl_xor(a1, 16, 64);
  a2 += __shfl_xor(a2, 16, 64); a3 += __shfl_xor(a3, 16, 64);
  a0 += __shfl_xor(a0, 32, 64); a1 += __shfl_xor(a1, 32, 64);
  a2 += __shfl_xor(a2, 32, 64); a3 += __shfl_xor(a3, 32, 64);

  // ================= middle (per-lane, 4x redundant; validated) ============
  const float aq[4] = {a0, a1, a2, a3};
  float xp[4];
  #pragma unroll
  for (int q = 0; q < 4; ++q) {
    const float e = __expf(2.0f * (aq[q] + b_in[q]));
    xp[q] = 1.0f - __fdividef(2.0f, e + 1.0f);   // tanh, inf-safe
  }
  const float mu = 0.25f * (xp[0] + xp[1] + xp[2] + xp[3]);
  const float d0 = xp[0] - mu, d1 = xp[1] - mu, d2 = xp[2] - mu, d3 = xp[3] - mu;
  const float var = 0.25f * (d0 * d0 + d1 * d1 + d2 * d2 + d3 * d3);
  const float inv = rsqrtf(var + 1e-5f);

  float A0[4], A1[4], A2[4], A3[4];   // a_i = (1, Ax, Ay, Az)
  #pragma unroll
  for (int i = 0; i < 4; ++i) {
    const float w0 = qw[i], w1 = qw[4 + i];
    const float cwa = cosf(w0), swa = sinf(w0);
    const float cwb = cosf(w1), swb = sinf(w1);
    const float ang = ((i == 0 ? d0 : i == 1 ? d1 : i == 2 ? d2 : d3) * inv) * gamma[i] + beta[i];
    float sn, cs;
    __sincosf(ang, &sn, &cs);
    const float ax = sn * sn;                     // RX(t) then RZ(t)
    const float ay = -sn * cs;
    const float az = cs;
    const float ay2 = ay * cwa - az * swa;        // RX(w0)
    const float az2 = ay * swa + az * cwa;
    const float Axv = ax * cwb - ay2 * swb;       // RZ(w1)
    const float Ayv = ax * swb + ay2 * cwb;
    float* dst = (i == 0) ? A0 : (i == 1) ? A1 : (i == 2) ? A2 : A3;
    dst[0] = 1.0f; dst[1] = Axv; dst[2] = Ayv; dst[3] = az2;
  }

  // z_q = sum_j u_j * sum_a A2[a] * (M[q][j][4a..4a+3] . A3)   (v elided)
  float z[4];
  #pragma unroll
  for (int q = 0; q < 4; ++q) {
    const float* Mq = M + q * 256;
    float zq = 0.0f;
    #pragma unroll
    for (int j = 0; j < 16; ++j) {
      const float4 m0 = *reinterpret_cast<const float4*>(&Mq[j * 16 + 0]);
      const float4 m1 = *reinterpret_cast<const float4*>(&Mq[j * 16 + 4]);
      const float4 m2 = *reinterpret_cast<const float4*>(&Mq[j * 16 + 8]);
      const float4 m3 = *reinterpret_cast<const float4*>(&Mq[j * 16 + 12]);
      const float ww =
          A2[0] * (m0.x * A3[0] + m0.y * A3[1] + m0.z * A3[2] + m0.w * A3[3]) +
          A2[1] * (m1.x * A3[0] + m1.y * A3[1] + m1.z * A3[2] + m1.w * A3[3]) +
          A2[2] * (m2.x * A3[0] + m2.y * A3[1] + m2.z * A3[2] + m2.w * A3[3]) +
          A2[3] * (m3.x * A3[0] + m3.y * A3[1] + m3.z * A3[2] + m3.w * A3[3]);
      zq += (A0[j >> 2] * A1[j & 3]) * ww;         // u_j static idx
    }
    z[q] = zq;
  }

  // ================= epilogue: my quarter; x re-read L2/L3-hot =============
  #pragma unroll
  for (int j = 0; j < 16; ++j) {
    const int c0 = kq * 64 + j * 4;
    const float4 xv = *reinterpret_cast<const float4*>(&x[xbase + j * 4]);
    const float4 w0 = *reinterpret_cast<const float4*>(&Wout[(c0 + 0) * 4]);
    const float4 w1 = *reinterpret_cast<const float4*>(&Wout[(c0 + 1) * 4]);
    const float4 w2 = *reinterpret_cast<const float4*>(&Wout[(c0 + 2) * 4]);
    const float4 w3 = *reinterpret_cast<const float4*>(&Wout[(c0 + 3) * 4]);
    const float4 bv = *reinterpret_cast<const float4*>(&b_out[c0]);
    float4 o;
    o.x = xv.x + bv.x + z[0] * w0.x + z[1] * w0.y + z[2] * w0.z + z[3] * w0.w;
    o.y = xv.y + bv.y + z[0] * w1.x + z[1] * w1.y + z[2] * w1.z + z[3] * w1.w;
    o.z = xv.z + bv.z + z[0] * w2.x + z[1] * w2.y + z[2] * w2.z + z[3] * w2.w;
    o.w = xv.w + bv.w + z[0] * w3.x + z[1] * w3.y + z[2] * w3.z + z[3] * w3.w;
    *reinterpret_cast<float4*>(&out[xbase + j * 4]) = o;
  }
}

extern "C" void kernel_launch(void* const* d_in, const int* in_sizes, int n_in,
                              void* d_out, int out_size, void* d_ws, size_t ws_size,
                              hipStream_t stream)
{
  const float* x     = (const float*)d_in[0];
  const float* Win   = (const float*)d_in[1];
  const float* b_in  = (const float*)d_in[2];
  const float* gamma = (const float*)d_in[3];
  const float* beta  = (const float*)d_in[4];
  const float* qw    = (const float*)d_in[5];
  const float* Wout  = (const float*)d_in[6];
  const float* b_out = (const float*)d_in[7];
  float* out = (float*)d_out;
  float* M   = (float*)d_ws;            // M[4][16][16] = 4 KB
  const int B = in_sizes[0] / DIM;

  hipLaunchKernelGGL(qc_setup_kernel, dim3(4), dim3(256), 0, stream, qw, M);

  // 16 rows per wave, 4 waves per block -> B/64 blocks (1024 for B=65536).
  const int nblocks = (B + 63) / 64;
  hipLaunchKernelGGL(qlayer_main_kernel, dim3(nblocks), dim3(256), 0, stream,
                     x, Win, b_in, gamma, beta, qw, Wout, b_out, M, out, B);
}

// Round 22
// 52.142 us; speedup vs baseline: 2.1215x; 2.1215x over previous
//
#include <hip/hip_runtime.h>
#include <math.h>

#define DIM 256

// ---------------------------------------------------------------------------
// K0 setup (4 blocks, one per output qubit q): builds M[q] = T[q] reshaped as
// 16x16 over (j=p0*4+p1, k=p2*4+p3) in d_ws. Validated math (rounds 2-21).
// z_q(row) = sum_{j,k} u_j M[q][j][k] v_k,  u = a0(x)a1, v = a2(x)a3,
// a_i = (1, Ax_i, Ay_i, Az_i) Bloch components; depolarize folded as
// s^(1+nnz), s = 1-4*0.05/3.  Qubit q <-> index bit (3-q).
// ---------------------------------------------------------------------------
__global__ void qc_setup_kernel(const float* __restrict__ qw, float* __restrict__ T)
{
  __shared__ float Vr[16][16], Vi[16][16];
  __shared__ float Or[16][16], Oi[16][16];
  const int tid = threadIdx.x;
  const int r = tid >> 4, c = tid & 15;

  Vr[r][c] = (r == c) ? 1.0f : 0.0f;
  Vi[r][c] = 0.0f;
  __syncthreads();

  #pragma unroll 1
  for (int i = 0; i < 4; ++i) {
    const int cm = 8 >> i;             // control mask (qubit i)
    const int tm = 8 >> ((i + 1) & 3); // target mask (qubit (i+1)%4)
    // CNOT(control=i, target=(i+1)%4): row permutation
    {
      const int k = (r & cm) ? (r ^ tm) : r;
      const float nr = Vr[k][c], ni = Vi[k][c];
      __syncthreads();
      Vr[r][c] = nr; Vi[r][c] = ni;
      __syncthreads();
    }
    const float w  = qw[4 + i];        // qweights[1][i]
    const float ch = cosf(0.5f * w), sh = sinf(0.5f * w);
    // RY(w) on qubit i
    {
      const int m = 8 >> i;
      const int r0 = r & ~m, r1 = r | m;
      float u0, u1;
      if (r & m) { u0 = sh; u1 = ch; } else { u0 = ch; u1 = -sh; }
      const float nr = u0 * Vr[r0][c] + u1 * Vr[r1][c];
      const float ni = u0 * Vi[r0][c] + u1 * Vi[r1][c];
      __syncthreads();
      Vr[r][c] = nr; Vi[r][c] = ni;
      __syncthreads();
    }
    // RZ(w) on qubit i (diagonal)
    {
      const int m = 8 >> i;
      const float pr = ch;
      const float pi = (r & m) ? sh : -sh;
      const float vr = Vr[r][c], vi = Vi[r][c];
      Vr[r][c] = pr * vr - pi * vi;
      Vi[r][c] = pr * vi + pi * vr;
      __syncthreads();
    }
  }

  const int q  = blockIdx.x;           // one q per block
  const int zm = 8 >> q;
  // O[r][c] = sum_k conj(V[k][r]) * sign_q(k) * V[k][c]
  float orr = 0.0f, oii = 0.0f;
  for (int k = 0; k < 16; ++k) {
    const float sgn = (k & zm) ? -1.0f : 1.0f;
    const float ar = Vr[k][r], ai = -Vi[k][r];
    const float br = Vr[k][c], bi = Vi[k][c];
    orr += sgn * (ar * br - ai * bi);
    oii += sgn * (ar * bi + ai * br);
  }
  __syncthreads();
  Or[r][c] = orr; Oi[r][c] = oii;
  __syncthreads();

  // thread tid <-> Pauli string p; Tr(P O) = sum_n P[n][m(n)] * O[m(n)][n]
  const float sdep = 1.0f - 4.0f * 0.05f / 3.0f;
  const int p0 = tid >> 6, p1 = (tid >> 4) & 3, p2 = (tid >> 2) & 3, p3 = tid & 3;
  float tr = 0.0f;
  for (int n = 0; n < 16; ++n) {
    int m = n;
    float fr = 1.0f, fi = 0.0f;
    #pragma unroll
    for (int i2 = 0; i2 < 4; ++i2) {
      const int a   = (n >> (3 - i2)) & 1;
      const int pi_ = (i2 == 0) ? p0 : (i2 == 1) ? p1 : (i2 == 2) ? p2 : p3;
      if (pi_ == 1) {                    // X
        m ^= (8 >> i2);
      } else if (pi_ == 2) {             // Y
        m ^= (8 >> i2);
        const float s2  = a ? 1.0f : -1.0f;
        const float nfr = -fi * s2, nfi = fr * s2;
        fr = nfr; fi = nfi;
      } else if (pi_ == 3) {             // Z
        if (a) { fr = -fr; fi = -fi; }
      }
    }
    tr += fr * Or[m][n] - fi * Oi[m][n];
  }
  const int nnz = (p0 != 0) + (p1 != 0) + (p2 != 0) + (p3 != 0);
  float scale = 1.0f / 16.0f;
  for (int e = 0; e <= nnz; ++e) scale *= sdep;
  T[q * 256 + tid] = tr * scale;
}

// ---------------------------------------------------------------------------
// Main kernel (round-22 = round-14 halved: 2048 blocks x 256 thr, 32 rows).
// r14 (48.6us main) was single-shot 1024 blocks = EXACTLY 4 blocks/CU, all
// phase-synchronized: burst-load -> compute -> burst-store -> straggler tail
// (occupancy 31% despite 32-wave eligibility). Halving block size doubles
// block count -> 8 blocks/CU co-resident, de-correlated phases + backfill.
// Per-wave work and register budget IDENTICAL to the proven r14 allocation.
//   A: each wave reg-tiles 8 rows (xr[8] float4); paired butterfly; accs->LDS.
//   B: wave 0, thread = row (32 lanes): tanh+LN+Bloch + bilinear z=u^T M_q v.
//   C: each wave epilogues its 8 rows from xr regs + broadcast zz read.
// ---------------------------------------------------------------------------
__global__ __launch_bounds__(256)
__attribute__((amdgpu_waves_per_eu(4, 8)))
void qlayer_main_kernel(
    const float* __restrict__ x,
    const float* __restrict__ Win,
    const float* __restrict__ b_in,
    const float* __restrict__ gamma,
    const float* __restrict__ beta,
    const float* __restrict__ qw,
    const float* __restrict__ Wout,
    const float* __restrict__ b_out,
    const float* __restrict__ M,
    float* __restrict__ out,
    int B)
{
  __shared__ float accs[32][4];
  __shared__ float zz[32][4];

  const int tid  = threadIdx.x;
  const int lane = tid & 63;
  const int wv   = tid >> 6;                    // wave 0..3
  const int lrow0 = wv * 8;                     // this wave's local rows
  const size_t grow0 = (size_t)blockIdx.x * 32 + lrow0;

  // ================= Phase A: reg-tile GEMV + paired reduce ================
  float4 winf[4];
  #pragma unroll
  for (int q = 0; q < 4; ++q)
    winf[q] = *reinterpret_cast<const float4*>(&Win[q * 256 + lane * 4]);

  float4 xr[8];
  #pragma unroll
  for (int i = 0; i < 8; ++i)
    xr[i] = *reinterpret_cast<const float4*>(&x[(grow0 + i) * DIM + lane * 4]);

  #pragma unroll
  for (int p = 0; p < 4; ++p) {
    float aA[4], aB[4];
    const float4 xa = xr[p * 2], xb = xr[p * 2 + 1];
    #pragma unroll
    for (int q = 0; q < 4; ++q) {
      aA[q] = xa.x * winf[q].x + xa.y * winf[q].y + xa.z * winf[q].z + xa.w * winf[q].w;
      aB[q] = xb.x * winf[q].x + xb.y * winf[q].y + xb.z * winf[q].z + xb.w * winf[q].w;
    }
    // fold the two 32-halves, pack row-pair into half-waves, 5-step butterfly
    #pragma unroll
    for (int q = 0; q < 4; ++q) {
      aA[q] += __shfl_xor(aA[q], 32, 64);
      aB[q] += __shfl_xor(aB[q], 32, 64);
      aA[q] = (lane < 32) ? aA[q] : aB[q];
    }
    #pragma unroll
    for (int off = 1; off < 32; off <<= 1) {
      #pragma unroll
      for (int q = 0; q < 4; ++q) aA[q] += __shfl_xor(aA[q], off, 64);
    }
    if ((lane & 31) == 0) {
      const int lr = lrow0 + p * 2 + (lane >> 5);
      *reinterpret_cast<float4*>(&accs[lr][0]) = make_float4(aA[0], aA[1], aA[2], aA[3]);
    }
  }
  __syncthreads();

  // ================= Phase B: wave 0, thread = row (32 lanes) ==============
  if (tid < 32) {
    const float4 av = *reinterpret_cast<const float4*>(&accs[tid][0]);
    const float aq[4] = {av.x, av.y, av.z, av.w};

    float xp[4];
    #pragma unroll
    for (int q = 0; q < 4; ++q) {
      const float e = __expf(2.0f * (aq[q] + b_in[q]));
      xp[q] = 1.0f - __fdividef(2.0f, e + 1.0f);   // tanh, inf-safe
    }
    const float mu = 0.25f * (xp[0] + xp[1] + xp[2] + xp[3]);
    const float d0 = xp[0] - mu, d1 = xp[1] - mu, d2 = xp[2] - mu, d3 = xp[3] - mu;
    const float var = 0.25f * (d0 * d0 + d1 * d1 + d2 * d2 + d3 * d3);
    const float inv = rsqrtf(var + 1e-5f);

    float A0[4], A1[4], A2[4], A3[4];   // a_i = (1, Ax, Ay, Az)
    #pragma unroll
    for (int i = 0; i < 4; ++i) {
      const float w0 = qw[i], w1 = qw[4 + i];
      const float cwa = cosf(w0), swa = sinf(w0);
      const float cwb = cosf(w1), swb = sinf(w1);
      const float ang = ((i == 0 ? d0 : i == 1 ? d1 : i == 2 ? d2 : d3) * inv) * gamma[i] + beta[i];
      float sn, cs;
      __sincosf(ang, &sn, &cs);
      const float ax = sn * sn;                     // RX(t) then RZ(t)
      const float ay = -sn * cs;
      const float az = cs;
      const float ay2 = ay * cwa - az * swa;        // RX(w0)
      const float az2 = ay * swa + az * cwa;
      const float Axv = ax * cwb - ay2 * swb;       // RZ(w1)
      const float Ayv = ax * swb + ay2 * cwb;
      float* dst = (i == 0) ? A0 : (i == 1) ? A1 : (i == 2) ? A2 : A3;
      dst[0] = 1.0f; dst[1] = Axv; dst[2] = Ayv; dst[3] = az2;
    }

    float v[16];
    #pragma unroll
    for (int a = 0; a < 4; ++a)
      #pragma unroll
      for (int b = 0; b < 4; ++b)
        v[a * 4 + b] = A2[a] * A3[b];

    float z[4];
    #pragma unroll
    for (int q = 0; q < 4; ++q) {
      float zq = 0.0f;
      #pragma unroll
      for (int j = 0; j < 16; ++j) {
        const float* Mr = &M[(q * 16 + j) * 16];   // wave-uniform -> s_load
        float w = 0.0f;
        #pragma unroll
        for (int k = 0; k < 16; ++k) w += Mr[k] * v[k];
        zq += (A0[j >> 2] * A1[j & 3]) * w;        // u_j inlined (static idx)
      }
      z[q] = zq;
    }
    *reinterpret_cast<float4*>(&zz[tid][0]) = make_float4(z[0], z[1], z[2], z[3]);
  }
  __syncthreads();

  // ================= Phase C: epilogue from regs + broadcast z =============
  float4 woutf[4];
  #pragma unroll
  for (int j = 0; j < 4; ++j)
    woutf[j] = *reinterpret_cast<const float4*>(&Wout[(lane * 4 + j) * 4]);
  const float4 boutf = *reinterpret_cast<const float4*>(&b_out[lane * 4]);

  #pragma unroll
  for (int i = 0; i < 8; ++i) {
    const float4 zv = *reinterpret_cast<const float4*>(&zz[lrow0 + i][0]);  // broadcast
    const float4 xv = xr[i];
    float4 o;
    o.x = xv.x + boutf.x + zv.x * woutf[0].x + zv.y * woutf[0].y + zv.z * woutf[0].z + zv.w * woutf[0].w;
    o.y = xv.y + boutf.y + zv.x * woutf[1].x + zv.y * woutf[1].y + zv.z * woutf[1].z + zv.w * woutf[1].w;
    o.z = xv.z + boutf.z + zv.x * woutf[2].x + zv.y * woutf[2].y + zv.z * woutf[2].z + zv.w * woutf[2].w;
    o.w = xv.w + boutf.w + zv.x * woutf[3].x + zv.y * woutf[3].y + zv.z * woutf[3].z + zv.w * woutf[3].w;
    *reinterpret_cast<float4*>(&out[(grow0 + i) * DIM + lane * 4]) = o;
  }
}

extern "C" void kernel_launch(void* const* d_in, const int* in_sizes, int n_in,
                              void* d_out, int out_size, void* d_ws, size_t ws_size,
                              hipStream_t stream)
{
  const float* x     = (const float*)d_in[0];
  const float* Win   = (const float*)d_in[1];
  const float* b_in  = (const float*)d_in[2];
  const float* gamma = (const float*)d_in[3];
  const float* beta  = (const float*)d_in[4];
  const float* qw    = (const float*)d_in[5];
  const float* Wout  = (const float*)d_in[6];
  const float* b_out = (const float*)d_in[7];
  float* out = (float*)d_out;
  float* T   = (float*)d_ws;            // M[4][16][16] = 4 KB
  const int B = in_sizes[0] / DIM;

  hipLaunchKernelGGL(qc_setup_kernel, dim3(4), dim3(256), 0, stream, qw, T);

  const int nblocks = B / 32;                       // 2048 for B=65536
  hipLaunchKernelGGL(qlayer_main_kernel, dim3(nblocks), dim3(256), 0, stream,
                     x, Win, b_in, gamma, beta, qw, Wout, b_out, T, out, B);
}